// Round 6
// baseline (450.235 us; speedup 1.0000x reference)
//
#include <hip/hip_runtime.h>

// Problem constants
#define DIMX 256
#define NMX  32768   // N*M tokens per batch
#define TB   64      // tokens per workgroup
#define PITCH 544    // main LDS row pitch (34*16B; 34 mod 8 = 2 -> swizzle-clean)
#define APITCH 288   // aux LDS row pitch (18*16B; 18 mod 8 = 2 -> same algebra)

typedef short s16x8 __attribute__((ext_vector_type(8)));  // 8 bf16 in 4 VGPRs
typedef float f32x4 __attribute__((ext_vector_type(4)));

// ws layout (bytes): packed bf16 A-fragments per matrix, then fp32 Wkv temp
#define OFF_WQN   (0u)        // -Wq  (K=256,E=256) 128KB
#define OFF_WK    (131072u)   //  Wk                128KB
#define OFF_WKV   (262144u)   //  Wk@Wv             128KB
#define OFF_W1    (393216u)   //  W1  (K=256,E=128)  64KB
#define OFF_W2    (458752u)   //  W2  (K=128,E=256)  64KB
#define OFF_WO    (524288u)   //  Wo                128KB
#define OFF_KVF32 (655360u)   //  fp32 Wkv temp     256KB

__device__ __forceinline__ ushort f2bf(float f) {
  uint u = __builtin_bit_cast(uint, f);
  return (ushort)((u + 0x7FFFu + ((u >> 16) & 1u)) >> 16);  // RNE
}

// packed pair f32x2 -> 2xbf16 in one VALU op (gfx950 v_cvt_pk_bf16_f32, RNE)
__device__ __forceinline__ uint cvtpk(float lo, float hi) {
  uint r;
  asm("v_cvt_pk_bf16_f32 %0, %1, %2" : "=v"(r) : "v"(lo), "v"(hi));
  return r;
}
__device__ __forceinline__ float bf_lo(uint u) {
  return __builtin_bit_cast(float, u << 16);
}
__device__ __forceinline__ float bf_hi(uint u) {
  return __builtin_bit_cast(float, u & 0xffff0000u);
}

// K0: Wkv = Wk @ Wv in fp32 (256x256x256, trivial)
__global__ void wkv_kernel(const float* __restrict__ Wk, const float* __restrict__ Wv,
                           float* __restrict__ outw) {
  const int e = threadIdx.x, d = blockIdx.x;
  float acc = 0.f;
  #pragma unroll 8
  for (int m = 0; m < DIMX; ++m) acc += Wk[d * DIMX + m] * Wv[m * DIMX + e];
  outw[d * DIMX + e] = acc;
}

// K1: pack all weights into MFMA A-fragment order, bf16.
__global__ void pack_kernel(const float* __restrict__ Wq, const float* __restrict__ Wk,
                            const float* __restrict__ Wkvf, const float* __restrict__ W1,
                            const float* __restrict__ W2, const float* __restrict__ Wo,
                            ushort* __restrict__ wsout) {
  const int fid = blockIdx.x, lane = threadIdx.x;  // 640 blocks x 64 threads
  const float* src; int Eout = 256; float sgn = 1.f; uint off; int local;
  if (fid < 128)      { src = Wq;   sgn = -1.f; off = OFF_WQN; local = fid;       }
  else if (fid < 256) { src = Wk;   off = OFF_WK;  local = fid - 128;             }
  else if (fid < 384) { src = Wkvf; off = OFF_WKV; local = fid - 256;             }
  else if (fid < 448) { src = W1;   Eout = 128; off = OFF_W1; local = fid - 384;  }
  else if (fid < 512) { src = W2;   off = OFF_W2;  local = fid - 448;             }
  else                { src = Wo;   off = OFF_WO;  local = fid - 512;             }
  const int R  = Eout >> 4;
  const int ks = local / R, r = local - ks * R;
  const int e  = r * 16 + (lane & 15);
  const int k0 = ks * 32 + (lane >> 4) * 8;
  union { uint4 u4; ushort us[8]; } o;
  #pragma unroll
  for (int j = 0; j < 8; ++j) o.us[j] = f2bf(sgn * src[(k0 + j) * Eout + e]);
  *(uint4*)((char*)wsout + off + (((uint)local * 64u + (uint)lane) * 16u)) = o.u4;
}

// Main fused kernel. WG = 64 tokens of one batch, 8 waves; wave w owns output
// rows [w*32, w*32+32) (rows [w*16,w*16+16) for the 128-wide hidden stage).
// LDS 52KB -> 3 WG/CU (24 waves/CU):
//   mb 34KB [t][d]     pitch 544B : k -> attn -> x
//   ab 18KB [t][d/2]   pitch 288B : q-lo -> q-hi -> h
// Both pitches are ≡2 mod 8 in 16B units + XOR swizzle ((t&7)<<4): all b128
// reads/writes hit each bank-quad at the hardware floor (conflict-free).
// q-hi is preloaded into registers before B1 so its HBM latency never sits
// between barriers.
#define MFMA16(A,B,C) __builtin_amdgcn_mfma_f32_16x16x32_bf16(A, B, C, 0, 0, 0)

__global__ __launch_bounds__(512, 6) void fused_main(
    const float* __restrict__ q, const float* __restrict__ kin,
    const float* __restrict__ pos, const int* __restrict__ mask,
    const float* __restrict__ b1, const float* __restrict__ b2,
    const float* __restrict__ bo, const ushort* __restrict__ wfr,
    float* __restrict__ out)
{
  __shared__ __align__(128) char mb[TB * PITCH];   // 34KB
  __shared__ __align__(128) char ab[TB * APITCH];  // 18KB
  const char* wb = (const char*)wfr;

  const int tid = threadIdx.x;
  const int w = tid >> 6, l = tid & 63;
  const int c = l & 15, g = l >> 4;
  const int b  = blockIdx.x >> 9;           // 512 token-blocks per batch
  const int t0 = (blockIdx.x & 511) * TB;

  // B-fragment reads: lane supplies B[k = ks*32 + g*8 + j][t = tf*16 + c]
  auto ldBm = [&](int ks, int tf) -> s16x8 {   // main, ks 0..7
    const int t = (tf << 4) + c;
    const int col = (ks << 6) + (g << 4);
    return *(const s16x8*)(mb + t * PITCH + (col ^ ((t & 7) << 4)));
  };
  auto ldBa = [&](int ks, int tf) -> s16x8 {   // aux, ks 0..3
    const int t = (tf << 4) + c;
    const int col = (ks << 6) + (g << 4);
    return *(const s16x8*)(ab + t * APITCH + (col ^ ((t & 7) << 4)));
  };
  // A-fragment (weights) from packed global, 16B/lane
  auto ldA = [&](uint moff, int fi) -> s16x8 {
    return *(const s16x8*)(wb + moff + (((uint)fi << 6) | (uint)l) * 16u);
  };
  // write 4 consecutive-e bf16 values (packed lo,hi) at (e0, t)
  auto stM4 = [&](int e0, int t, uint lo, uint hi) {
    const int byte = t * PITCH + (((uint)(e0 * 2)) ^ ((t & 7) << 4));
    *(uint2*)(mb + byte) = uint2{lo, hi};
  };
  auto stA4 = [&](int e0, int t, uint lo, uint hi) {
    const int byte = t * APITCH + (((uint)(e0 * 2)) ^ ((t & 7) << 4));
    *(uint2*)(ab + byte) = uint2{lo, hi};
  };

  const size_t gbase = (size_t)b * DIMX * NMX + t0 + l;

  // ---- stage k (full) -> mb, q-lo -> ab; preload q-hi into regs; nt loads ----
  #pragma unroll
  for (int j4 = 0; j4 < 4; ++j4) {
    const int d0 = (w << 5) + (j4 << 3);
    uint pk[4];
    #pragma unroll
    for (int p = 0; p < 4; ++p) {
      const size_t o0 = gbase + (size_t)(d0 + 2 * p) * NMX;
      pk[p] = cvtpk(__builtin_nontemporal_load(kin + o0),
                    __builtin_nontemporal_load(kin + o0 + NMX));
    }
    const int byte = l * PITCH + ((d0 << 1) ^ ((l & 7) << 4));
    *(uint4*)(mb + byte) = uint4{pk[0], pk[1], pk[2], pk[3]};
  }
  #pragma unroll
  for (int j4 = 0; j4 < 2; ++j4) {
    const int dl = (w << 4) + (j4 << 3);     // q-lo: d = dl
    uint pq[4];
    #pragma unroll
    for (int p = 0; p < 4; ++p) {
      const size_t o0 = gbase + (size_t)(dl + 2 * p) * NMX;
      pq[p] = cvtpk(__builtin_nontemporal_load(q + o0),
                    __builtin_nontemporal_load(q + o0 + NMX));
    }
    const int byte = l * APITCH + ((dl << 1) ^ ((l & 7) << 4));
    *(uint4*)(ab + byte) = uint4{pq[0], pq[1], pq[2], pq[3]};
  }
  uint qh[8];                                // q-hi: d = 128 + dl (regs only)
  #pragma unroll
  for (int j4 = 0; j4 < 2; ++j4) {
    const int d = 128 + (w << 4) + (j4 << 3);
    #pragma unroll
    for (int p = 0; p < 4; ++p) {
      const size_t o0 = gbase + (size_t)(d + 2 * p) * NMX;
      qh[j4 * 4 + p] = cvtpk(__builtin_nontemporal_load(q + o0),
                             __builtin_nontemporal_load(q + o0 + NMX));
    }
  }

  // ---- issue pos + mask loads BEFORE the barrier (latency hides under it) ----
  f32x4 posr[4][2];
  {
    const float* pz = pos + ((size_t)b * NMX + t0) * DIMX;
    #pragma unroll
    for (int tf = 0; tf < 4; ++tf) {
      const int t = (tf << 4) + c;
      #pragma unroll
      for (int ef = 0; ef < 2; ++ef) {
        const int e0 = (w << 5) + (ef << 4) + (g << 2);
        posr[tf][ef] =
            __builtin_nontemporal_load((const f32x4*)(pz + (size_t)t * DIMX + e0));
      }
    }
  }
  int mk[4];
  #pragma unroll
  for (int tf = 0; tf < 4; ++tf)
    mk[tf] = mask[(size_t)b * NMX + t0 + (tf << 4) + c];

  __syncthreads();   // B1: k + q-lo staged

  // pos -> bf16 (frees 16 regs; stall mostly absorbed by the barrier)
  uint posbf[2][4][2];
  #pragma unroll
  for (int tf = 0; tf < 4; ++tf)
    #pragma unroll
    for (int ef = 0; ef < 2; ++ef) {
      posbf[ef][tf][0] = cvtpk(posr[tf][ef][0], posr[tf][ef][1]);
      posbf[ef][tf][1] = cvtpk(posr[tf][ef][2], posr[tf][ef][3]);
    }

  // ---- phase 2ab (fused): av = Wkv^T k, aa = Wk^T k — shared B-fragments ----
  f32x4 av[2][4], aa[2][4];
  #pragma unroll
  for (int ef = 0; ef < 2; ++ef)
    #pragma unroll
    for (int tf = 0; tf < 4; ++tf) {
      av[ef][tf] = f32x4{0.f, 0.f, 0.f, 0.f};
      aa[ef][tf] = f32x4{0.f, 0.f, 0.f, 0.f};
    }
  #pragma unroll 2
  for (int ks = 0; ks < 8; ++ks) {
    const s16x8 v0 = ldA(OFF_WKV, (ks << 4) + (w << 1));
    const s16x8 v1 = ldA(OFF_WKV, (ks << 4) + (w << 1) + 1);
    const s16x8 k0 = ldA(OFF_WK,  (ks << 4) + (w << 1));
    const s16x8 k1 = ldA(OFF_WK,  (ks << 4) + (w << 1) + 1);
    #pragma unroll
    for (int tf = 0; tf < 4; ++tf) {
      const s16x8 bf = ldBm(ks, tf);
      av[0][tf] = MFMA16(v0, bf, av[0][tf]);
      av[1][tf] = MFMA16(v1, bf, av[1][tf]);
      aa[0][tf] = MFMA16(k0, bf, aa[0][tf]);
      aa[1][tf] = MFMA16(k1, bf, aa[1][tf]);
    }
  }
  // pack v to bf16 (av dies)
  uint vbf[2][4][2];
  #pragma unroll
  for (int ef = 0; ef < 2; ++ef)
    #pragma unroll
    for (int tf = 0; tf < 4; ++tf) {
      vbf[ef][tf][0] = cvtpk(av[ef][tf][0], av[ef][tf][1]);
      vbf[ef][tf][1] = cvtpk(av[ef][tf][2], av[ef][tf][3]);
    }

  // ---- phase 2c-lo: aa += (-Wq)^T q-lo (global ks 0..3) ----
  #pragma unroll 2
  for (int ks = 0; ks < 4; ++ks) {
    const s16x8 a0 = ldA(OFF_WQN, (ks << 4) + (w << 1));
    const s16x8 a1 = ldA(OFF_WQN, (ks << 4) + (w << 1) + 1);
    #pragma unroll
    for (int tf = 0; tf < 4; ++tf) {
      const s16x8 bf = ldBa(ks, tf);
      aa[0][tf] = MFMA16(a0, bf, aa[0][tf]);
      aa[1][tf] = MFMA16(a1, bf, aa[1][tf]);
    }
  }
  __syncthreads();   // B2: q-lo consumed by all waves

  // ---- q-hi regs -> ab (no global latency here) ----
  #pragma unroll
  for (int j4 = 0; j4 < 2; ++j4) {
    const int dl = (w << 4) + (j4 << 3);
    const int byte = l * APITCH + ((dl << 1) ^ ((l & 7) << 4));
    *(uint4*)(ab + byte) = uint4{qh[j4 * 4], qh[j4 * 4 + 1],
                                 qh[j4 * 4 + 2], qh[j4 * 4 + 3]};
  }
  __syncthreads();   // B3: q-hi staged

  // ---- phase 2c-hi: aa += (-Wq)^T q-hi (global ks 4..7) ----
  #pragma unroll 2
  for (int ks = 4; ks < 8; ++ks) {
    const s16x8 a0 = ldA(OFF_WQN, (ks << 4) + (w << 1));
    const s16x8 a1 = ldA(OFF_WQN, (ks << 4) + (w << 1) + 1);
    #pragma unroll
    for (int tf = 0; tf < 4; ++tf) {
      const s16x8 bf = ldBa(ks - 4, tf);
      aa[0][tf] = MFMA16(a0, bf, aa[0][tf]);
      aa[1][tf] = MFMA16(a1, bf, aa[1][tf]);
    }
  }
  // (no barrier needed before attn write: k in mb is dead, each wave writes
  //  its own rows — but other waves may still be reading mb rows in 2c-hi?
  //  No: 2c-hi reads only ab. mb reads ended at B2.)

  // ---- attn = aa + pos -> bf16 -> mb rows [w*32,+32) ----
  #pragma unroll
  for (int tf = 0; tf < 4; ++tf) {
    const int t = (tf << 4) + c;
    #pragma unroll
    for (int ef = 0; ef < 2; ++ef) {
      const int e0 = (w << 5) + (ef << 4) + (g << 2);
      const uint p0 = posbf[ef][tf][0], p1 = posbf[ef][tf][1];
      const uint lo = cvtpk(aa[ef][tf][0] + bf_lo(p0), aa[ef][tf][1] + bf_hi(p0));
      const uint hi = cvtpk(aa[ef][tf][2] + bf_lo(p1), aa[ef][tf][3] + bf_hi(p1));
      stM4(e0, t, lo, hi);
    }
  }
  __syncthreads();   // B4: attn tile complete

  // ---- phase 5: h = relu(W1^T attn + b1) -> ab rows [w*16,+16) ----
  f32x4 ah[4];
  #pragma unroll
  for (int tf = 0; tf < 4; ++tf) ah[tf] = f32x4{0.f, 0.f, 0.f, 0.f};
  #pragma unroll 2
  for (int ks = 0; ks < 8; ++ks) {
    const s16x8 a0 = ldA(OFF_W1, (ks << 3) + w);
    #pragma unroll
    for (int tf = 0; tf < 4; ++tf) {
      const s16x8 bf = ldBm(ks, tf);
      ah[tf] = MFMA16(a0, bf, ah[tf]);
    }
  }
  {
    const int e0h = (w << 4) + (g << 2);
    const f32x4 b1v = *(const f32x4*)(b1 + e0h);
    #pragma unroll
    for (int tf = 0; tf < 4; ++tf) {
      const int t = (tf << 4) + c;
      const uint lo = cvtpk(fmaxf(ah[tf][0] + b1v[0], 0.f),
                            fmaxf(ah[tf][1] + b1v[1], 0.f));
      const uint hi = cvtpk(fmaxf(ah[tf][2] + b1v[2], 0.f),
                            fmaxf(ah[tf][3] + b1v[3], 0.f));
      stA4(e0h, t, lo, hi);
    }
  }
  __syncthreads();   // B5: h tile complete

  // ---- phase 6: a2 = W2^T h + b2; mask; sigmoid; x = (v+pos)*sig -> mb ----
  f32x4 as_[2][4];
  #pragma unroll
  for (int ef = 0; ef < 2; ++ef)
    #pragma unroll
    for (int tf = 0; tf < 4; ++tf) as_[ef][tf] = f32x4{0.f, 0.f, 0.f, 0.f};
  #pragma unroll
  for (int ks = 0; ks < 4; ++ks) {
    const s16x8 a0 = ldA(OFF_W2, (ks << 4) + (w << 1));
    const s16x8 a1 = ldA(OFF_W2, (ks << 4) + (w << 1) + 1);
    #pragma unroll
    for (int tf = 0; tf < 4; ++tf) {
      const s16x8 bf = ldBa(ks, tf);
      as_[0][tf] = MFMA16(a0, bf, as_[0][tf]);
      as_[1][tf] = MFMA16(a1, bf, as_[1][tf]);
    }
  }
  #pragma unroll
  for (int tf = 0; tf < 4; ++tf) {
    const int t = (tf << 4) + c;
    #pragma unroll
    for (int ef = 0; ef < 2; ++ef) {
      const int e0 = (w << 5) + (ef << 4) + (g << 2);
      const f32x4 b2v = *(const f32x4*)(b2 + e0);
      float xv[4];
      #pragma unroll
      for (int i = 0; i < 4; ++i) {
        float sv = as_[ef][tf][i] + b2v[i];
        if (mk[tf] == 0) sv = -1e9f;
        const float sig = 1.f / (1.f + __expf(-sv));
        const uint pv = vbf[ef][tf][i >> 1];
        const uint pp = posbf[ef][tf][i >> 1];
        const float vv = (i & 1) ? bf_hi(pv) : bf_lo(pv);
        const float pf = (i & 1) ? bf_hi(pp) : bf_lo(pp);
        xv[i] = (vv + pf) * sig;
      }
      stM4(e0, t, cvtpk(xv[0], xv[1]), cvtpk(xv[2], xv[3]));
    }
  }
  __syncthreads();   // B6: x tile complete

  // ---- phase 7: out = Wo^T x + bo -> (B, D, N, M) ----
  f32x4 ao[2][4];
  #pragma unroll
  for (int ef = 0; ef < 2; ++ef)
    #pragma unroll
    for (int tf = 0; tf < 4; ++tf) ao[ef][tf] = f32x4{0.f, 0.f, 0.f, 0.f};
  #pragma unroll 2
  for (int ks = 0; ks < 8; ++ks) {
    const s16x8 a0 = ldA(OFF_WO, (ks << 4) + (w << 1));
    const s16x8 a1 = ldA(OFF_WO, (ks << 4) + (w << 1) + 1);
    #pragma unroll
    for (int tf = 0; tf < 4; ++tf) {
      const s16x8 bf = ldBm(ks, tf);
      ao[0][tf] = MFMA16(a0, bf, ao[0][tf]);
      ao[1][tf] = MFMA16(a1, bf, ao[1][tf]);
    }
  }
  #pragma unroll
  for (int ef = 0; ef < 2; ++ef) {
    const int e0 = (w << 5) + (ef << 4) + (g << 2);
    const f32x4 bov = *(const f32x4*)(bo + e0);
    #pragma unroll
    for (int i = 0; i < 4; ++i) {
      float* ob = out + ((size_t)b * DIMX + e0 + i) * NMX + t0 + c;
      #pragma unroll
      for (int tf = 0; tf < 4; ++tf)
        ob[tf << 4] = ao[ef][tf][i] + bov[i];
    }
  }
}

extern "C" void kernel_launch(void* const* d_in, const int* in_sizes, int n_in,
                              void* d_out, int out_size, void* d_ws, size_t ws_size,
                              hipStream_t stream) {
  (void)in_sizes; (void)n_in; (void)out_size; (void)ws_size;
  const float* q   = (const float*)d_in[0];
  const float* k   = (const float*)d_in[1];
  const float* pos = (const float*)d_in[2];
  const int*   msk = (const int*)d_in[3];
  const float* Wq  = (const float*)d_in[4];
  const float* Wk  = (const float*)d_in[5];
  const float* Wv  = (const float*)d_in[6];
  const float* W1  = (const float*)d_in[7];
  const float* b1  = (const float*)d_in[8];
  const float* W2  = (const float*)d_in[9];
  const float* b2  = (const float*)d_in[10];
  const float* Wo  = (const float*)d_in[11];
  const float* bo  = (const float*)d_in[12];
  float* out = (float*)d_out;
  char* ws = (char*)d_ws;
  float*  wkvf = (float*)(ws + OFF_KVF32);
  ushort* wfr  = (ushort*)ws;

  wkv_kernel<<<dim3(256), dim3(256), 0, stream>>>(Wk, Wv, wkvf);
  pack_kernel<<<dim3(640), dim3(64), 0, stream>>>(Wq, Wk, wkvf, W1, W2, Wo, wfr);
  fused_main<<<dim3(2048), dim3(512), 0, stream>>>(q, k, pos, msk, b1, b2, bo, wfr, out);
}

// Round 7
// 197.888 us; speedup vs baseline: 2.2752x; 2.2752x over previous
//
#include <hip/hip_runtime.h>

// Problem constants
#define DIMX 256
#define NMX  32768   // N*M tokens per batch
#define TB   64      // tokens per workgroup
#define PITCH 544    // LDS row pitch in bytes (34*16B; bank-rotation 8/row)

typedef short s16x8 __attribute__((ext_vector_type(8)));   // 8 bf16 in 4 VGPRs
typedef float f32x4 __attribute__((ext_vector_type(4)));
typedef float f32x16 __attribute__((ext_vector_type(16))); // 32x32 accumulator

// ws layout (bytes): packed bf16 A-fragments per matrix, then fp32 Wkv temp
#define OFF_WQN   (0u)        // -Wq  (K=256,E=256) 128KB  [32x32 frags]
#define OFF_WK    (131072u)   //  Wk                128KB  [32x32]
#define OFF_WKV   (262144u)   //  Wk@Wv             128KB  [32x32]
#define OFF_W1    (393216u)   //  W1  (K=256,E=128)  64KB  [16x16]
#define OFF_W2    (458752u)   //  W2  (K=128,E=256)  64KB  [32x32]
#define OFF_WO    (524288u)   //  Wo                128KB  [32x32]
#define OFF_KVF32 (655360u)   //  fp32 Wkv temp     256KB

__device__ __forceinline__ ushort f2bf(float f) {
  uint u = __builtin_bit_cast(uint, f);
  return (ushort)((u + 0x7FFFu + ((u >> 16) & 1u)) >> 16);  // RNE
}
__device__ __forceinline__ uint cvtpk(float lo, float hi) {
  uint r;
  asm("v_cvt_pk_bf16_f32 %0, %1, %2" : "=v"(r) : "v"(lo), "v"(hi));
  return r;
}
__device__ __forceinline__ float bf_lo(uint u) {
  return __builtin_bit_cast(float, u << 16);
}
__device__ __forceinline__ float bf_hi(uint u) {
  return __builtin_bit_cast(float, u & 0xffff0000u);
}

// K0: Wkv = Wk @ Wv in fp32 (256x256x256, trivial)
__global__ void wkv_kernel(const float* __restrict__ Wk, const float* __restrict__ Wv,
                           float* __restrict__ outw) {
  const int e = threadIdx.x, d = blockIdx.x;
  float acc = 0.f;
  #pragma unroll 8
  for (int m = 0; m < DIMX; ++m) acc += Wk[d * DIMX + m] * Wv[m * DIMX + e];
  outw[d * DIMX + e] = acc;
}

// K1: pack weights into MFMA A-fragment order, bf16.
// 32x32x16 frag (all but W1): value[lane][j] = W[ks*16+(lane>>5)*8+j][r*32+(lane&31)]
//   frag id = ks*8 + r  (ks 0..K/16-1, r = e-block/32)
// 16x16x32 frag (W1):       value[lane][j] = W[ks*32+(lane>>4)*8+j][r*16+(lane&15)]
// stored at off + (frag*64+lane)*16 bytes.
__global__ void pack_kernel(const float* __restrict__ Wq, const float* __restrict__ Wk,
                            const float* __restrict__ Wkvf, const float* __restrict__ W1,
                            const float* __restrict__ W2, const float* __restrict__ Wo,
                            ushort* __restrict__ wsout) {
  const int fid = blockIdx.x, lane = threadIdx.x;  // 640 blocks x 64 threads
  const float* src; int Eout = 256; float sgn = 1.f; uint off; int local; int m32 = 1;
  if (fid < 128)      { src = Wq;   sgn = -1.f; off = OFF_WQN; local = fid;       }
  else if (fid < 256) { src = Wk;   off = OFF_WK;  local = fid - 128;             }
  else if (fid < 384) { src = Wkvf; off = OFF_WKV; local = fid - 256;             }
  else if (fid < 448) { src = W1;   Eout = 128; m32 = 0; off = OFF_W1; local = fid - 384; }
  else if (fid < 512) { src = W2;   off = OFF_W2;  local = fid - 448;             }
  else                { src = Wo;   off = OFF_WO;  local = fid - 512;             }
  const int ks = local >> 3, r = local & 7;
  int e, k0;
  if (m32) { e = r * 32 + (lane & 31); k0 = ks * 16 + (lane >> 5) * 8; }
  else     { e = r * 16 + (lane & 15); k0 = ks * 32 + (lane >> 4) * 8; }
  union { uint4 u4; ushort us[8]; } o;
  #pragma unroll
  for (int j = 0; j < 8; ++j) o.us[j] = f2bf(sgn * src[(k0 + j) * Eout + e]);
  *(uint4*)((char*)wsout + off + (((uint)local * 64u + (uint)lane) * 16u)) = o.u4;
}

// Main fused kernel. WG = 64 tokens of one batch, 8 waves; wave w owns output
// rows [w*32, w*32+32) (rows [w*16,w*16+16) for the 16x16 W1 stage).
// 32x32x16 MFMA for WKV/WK/WQN/W2/WO (176 MFMA/wave vs 320 at 16x16).
// LDS: ba 34KB (q -> attn -> x), bb 34KB (k -> h); [t][d] bf16 pitch 544B +
// XOR swizzle ((t&7)<<4): b128 ops pair at most 2-way per 16-lane group (free).
#define MFMA16(A,B,C) __builtin_amdgcn_mfma_f32_16x16x32_bf16(A, B, C, 0, 0, 0)
#define MFMA32(A,B,C) __builtin_amdgcn_mfma_f32_32x32x16_bf16(A, B, C, 0, 0, 0)

__global__ __launch_bounds__(512, 4) void fused_main(
    const float* __restrict__ q, const float* __restrict__ kin,
    const float* __restrict__ pos, const int* __restrict__ mask,
    const float* __restrict__ b1, const float* __restrict__ b2,
    const float* __restrict__ bo, const ushort* __restrict__ wfr,
    float* __restrict__ out)
{
  __shared__ __align__(128) char ba[TB * PITCH];  // 34KB
  __shared__ __align__(128) char bb[TB * PITCH];  // 34KB
  const char* wb = (const char*)wfr;

  const int tid = threadIdx.x;
  const int w = tid >> 6, l = tid & 63;
  const int c = l & 15, g = l >> 4;        // 16x16 lane coords (W1)
  const int tl = l & 31, h2 = l >> 5;      // 32x32 lane coords
  const int b  = blockIdx.x >> 9;          // 512 token-blocks per batch
  const int t0 = (blockIdx.x & 511) * TB;

  // 32x32 B-frag: lane supplies B[k = ks*16 + h2*8 + j][t = tf*32 + tl]
  auto ldB32 = [&](const char* buf, int ks, int tf) -> s16x8 {
    const int t = (tf << 5) + tl;
    const int col = (ks << 5) + (h2 << 4);
    return *(const s16x8*)(buf + t * PITCH + (col ^ ((t & 7) << 4)));
  };
  // 16x16 B-frag (W1 only): B[k = ks*32 + g*8 + j][t = tf*16 + c]
  auto ldB16 = [&](const char* buf, int ks, int tf) -> s16x8 {
    const int t = (tf << 4) + c;
    const int col = (ks << 6) + (g << 4);
    return *(const s16x8*)(buf + t * PITCH + (col ^ ((t & 7) << 4)));
  };
  // A-fragment (weights) from packed global, 16B/lane
  auto ldA = [&](uint moff, int fi) -> s16x8 {
    return *(const s16x8*)(wb + moff + (((uint)fi << 6) | (uint)l) * 16u);
  };
  // write 4 consecutive-e bf16 values (packed lo,hi) at (e0, t)
  auto stW4 = [&](char* buf, int e0, int t, uint lo, uint hi) {
    const int byte = t * PITCH + (((uint)(e0 * 2)) ^ ((t & 7) << 4));
    *(uint2*)(buf + byte) = uint2{lo, hi};
  };

  const size_t gbase = (size_t)b * DIMX * NMX + t0 + l;

  // ---- stage q -> ba, k -> bb (transposed, bf16, swizzled); nt loads ----
  #pragma unroll
  for (int j4 = 0; j4 < 4; ++j4) {
    const int d0 = (w << 5) + (j4 << 3);
    uint pq[4], pk[4];
    #pragma unroll
    for (int p = 0; p < 4; ++p) {
      const size_t o0 = gbase + (size_t)(d0 + 2 * p) * NMX;
      const size_t o1 = o0 + NMX;
      pq[p] = cvtpk(__builtin_nontemporal_load(q + o0),
                    __builtin_nontemporal_load(q + o1));
      pk[p] = cvtpk(__builtin_nontemporal_load(kin + o0),
                    __builtin_nontemporal_load(kin + o1));
    }
    const int byte = l * PITCH + ((d0 << 1) ^ ((l & 7) << 4));
    *(uint4*)(ba + byte) = uint4{pq[0], pq[1], pq[2], pq[3]};
    *(uint4*)(bb + byte) = uint4{pk[0], pk[1], pk[2], pk[3]};
  }

  // ---- issue pos + mask loads BEFORE the barrier (latency hides under it) ----
  // lane's C elements: t = tf*32 + tl, e = w*32 + a*8 + h2*4 + bq
  f32x4 posr[2][4];
  {
    const float* pz = pos + ((size_t)b * NMX + t0) * DIMX;
    #pragma unroll
    for (int tf = 0; tf < 2; ++tf) {
      const int t = (tf << 5) + tl;
      #pragma unroll
      for (int a = 0; a < 4; ++a) {
        const int e0 = (w << 5) + (a << 3) + (h2 << 2);
        posr[tf][a] =
            __builtin_nontemporal_load((const f32x4*)(pz + (size_t)t * DIMX + e0));
      }
    }
  }
  int mk[2];
  #pragma unroll
  for (int tf = 0; tf < 2; ++tf)
    mk[tf] = mask[(size_t)b * NMX + t0 + (tf << 5) + tl];

  __syncthreads();   // B1: tiles staged

  // pos -> bf16 (frees 16 regs; stall mostly absorbed by the barrier)
  uint posbf[2][8];
  #pragma unroll
  for (int tf = 0; tf < 2; ++tf)
    #pragma unroll
    for (int a = 0; a < 4; ++a) {
      posbf[tf][2 * a]     = cvtpk(posr[tf][a][0], posr[tf][a][1]);
      posbf[tf][2 * a + 1] = cvtpk(posr[tf][a][2], posr[tf][a][3]);
    }

  // ---- phase 2ab (fused): av = Wkv^T k, aa = Wk^T k — shared B-fragments ----
  f32x16 av[2], aa[2];
  #pragma unroll
  for (int tf = 0; tf < 2; ++tf)
    #pragma unroll
    for (int i = 0; i < 16; ++i) { av[tf][i] = 0.f; aa[tf][i] = 0.f; }
  #pragma unroll 2
  for (int ks = 0; ks < 16; ++ks) {
    const s16x8 v0 = ldA(OFF_WKV, (ks << 3) + w);
    const s16x8 k0 = ldA(OFF_WK,  (ks << 3) + w);
    #pragma unroll
    for (int tf = 0; tf < 2; ++tf) {
      const s16x8 bf = ldB32(bb, ks, tf);
      av[tf] = MFMA32(v0, bf, av[tf]);
      aa[tf] = MFMA32(k0, bf, aa[tf]);
    }
  }
  // pack v to bf16 (av dies)
  uint vbf[2][8];
  #pragma unroll
  for (int tf = 0; tf < 2; ++tf)
    #pragma unroll
    for (int p = 0; p < 8; ++p)
      vbf[tf][p] = cvtpk(av[tf][2 * p], av[tf][2 * p + 1]);

  // ---- phase 2c: aa += (-Wq)^T q ----
  #pragma unroll 2
  for (int ks = 0; ks < 16; ++ks) {
    const s16x8 a0 = ldA(OFF_WQN, (ks << 3) + w);
    #pragma unroll
    for (int tf = 0; tf < 2; ++tf) {
      const s16x8 bf = ldB32(ba, ks, tf);
      aa[tf] = MFMA32(a0, bf, aa[tf]);
    }
  }
  __syncthreads();   // B2: q,k consumption done

  // ---- attn = aa + pos -> bf16 -> ba rows [w*32,+32) ----
  #pragma unroll
  for (int tf = 0; tf < 2; ++tf) {
    const int t = (tf << 5) + tl;
    #pragma unroll
    for (int a = 0; a < 4; ++a) {
      const int e0 = (w << 5) + (a << 3) + (h2 << 2);
      const uint p0 = posbf[tf][2 * a], p1 = posbf[tf][2 * a + 1];
      const uint lo = cvtpk(aa[tf][4 * a + 0] + bf_lo(p0),
                            aa[tf][4 * a + 1] + bf_hi(p0));
      const uint hi = cvtpk(aa[tf][4 * a + 2] + bf_lo(p1),
                            aa[tf][4 * a + 3] + bf_hi(p1));
      stW4(ba, e0, t, lo, hi);
    }
  }
  __syncthreads();   // B3: attn tile complete

  // ---- phase 5: h = relu(W1^T attn + b1) -> bb rows [w*16,+16)  (16x16) ----
  f32x4 ah[4];
  #pragma unroll
  for (int tf = 0; tf < 4; ++tf) ah[tf] = f32x4{0.f, 0.f, 0.f, 0.f};
  #pragma unroll 2
  for (int ks = 0; ks < 8; ++ks) {
    const s16x8 a0 = ldA(OFF_W1, (ks << 3) + w);
    #pragma unroll
    for (int tf = 0; tf < 4; ++tf) {
      const s16x8 bf = ldB16(ba, ks, tf);
      ah[tf] = MFMA16(a0, bf, ah[tf]);
    }
  }
  {
    const int e0h = (w << 4) + (g << 2);
    const f32x4 b1v = *(const f32x4*)(b1 + e0h);
    #pragma unroll
    for (int tf = 0; tf < 4; ++tf) {
      const int t = (tf << 4) + c;
      const uint lo = cvtpk(fmaxf(ah[tf][0] + b1v[0], 0.f),
                            fmaxf(ah[tf][1] + b1v[1], 0.f));
      const uint hi = cvtpk(fmaxf(ah[tf][2] + b1v[2], 0.f),
                            fmaxf(ah[tf][3] + b1v[3], 0.f));
      stW4(bb, e0h, t, lo, hi);
    }
  }
  __syncthreads();   // B4: h tile complete

  // ---- phase 6: a2 = W2^T h + b2; mask; sigmoid; x = (v+pos)*sig -> ba ----
  f32x16 as_[2];
  #pragma unroll
  for (int tf = 0; tf < 2; ++tf)
    #pragma unroll
    for (int i = 0; i < 16; ++i) as_[tf][i] = 0.f;
  #pragma unroll 2
  for (int ks = 0; ks < 8; ++ks) {
    const s16x8 a0 = ldA(OFF_W2, (ks << 3) + w);
    #pragma unroll
    for (int tf = 0; tf < 2; ++tf) {
      const s16x8 bf = ldB32(bb, ks, tf);
      as_[tf] = MFMA32(a0, bf, as_[tf]);
    }
  }
  #pragma unroll
  for (int tf = 0; tf < 2; ++tf) {
    const int t = (tf << 5) + tl;
    #pragma unroll
    for (int a = 0; a < 4; ++a) {
      const int e0 = (w << 5) + (a << 3) + (h2 << 2);
      const f32x4 b2v = *(const f32x4*)(b2 + e0);
      float xv[4];
      #pragma unroll
      for (int bq = 0; bq < 4; ++bq) {
        float sv = as_[tf][4 * a + bq] + b2v[bq];
        if (mk[tf] == 0) sv = -1e9f;
        const float sig = 1.f / (1.f + __expf(-sv));
        const uint pv = vbf[tf][2 * a + (bq >> 1)];
        const uint pp = posbf[tf][2 * a + (bq >> 1)];
        const float vv = (bq & 1) ? bf_hi(pv) : bf_lo(pv);
        const float pf = (bq & 1) ? bf_hi(pp) : bf_lo(pp);
        xv[bq] = (vv + pf) * sig;
      }
      stW4(ba, e0, t, cvtpk(xv[0], xv[1]), cvtpk(xv[2], xv[3]));
    }
  }
  __syncthreads();   // B5: x tile complete

  // ---- phase 7: out = Wo^T x + bo -> (B, D, N, M) ----
  f32x16 ao[2];
  #pragma unroll
  for (int tf = 0; tf < 2; ++tf)
    #pragma unroll
    for (int i = 0; i < 16; ++i) ao[tf][i] = 0.f;
  #pragma unroll 2
  for (int ks = 0; ks < 16; ++ks) {
    const s16x8 a0 = ldA(OFF_WO, (ks << 3) + w);
    #pragma unroll
    for (int tf = 0; tf < 2; ++tf) {
      const s16x8 bf = ldB32(ba, ks, tf);
      ao[tf] = MFMA32(a0, bf, ao[tf]);
    }
  }
  #pragma unroll
  for (int tf = 0; tf < 2; ++tf) {
    const int t = t0 + (tf << 5) + tl;
    #pragma unroll
    for (int a = 0; a < 4; ++a) {
      const int e0 = (w << 5) + (a << 3) + (h2 << 2);
      const f32x4 bov = *(const f32x4*)(bo + e0);
      #pragma unroll
      for (int bq = 0; bq < 4; ++bq)
        out[((size_t)b * DIMX + e0 + bq) * NMX + t] = ao[tf][4 * a + bq] + bov[bq];
    }
  }
}

extern "C" void kernel_launch(void* const* d_in, const int* in_sizes, int n_in,
                              void* d_out, int out_size, void* d_ws, size_t ws_size,
                              hipStream_t stream) {
  (void)in_sizes; (void)n_in; (void)out_size; (void)ws_size;
  const float* q   = (const float*)d_in[0];
  const float* k   = (const float*)d_in[1];
  const float* pos = (const float*)d_in[2];
  const int*   msk = (const int*)d_in[3];
  const float* Wq  = (const float*)d_in[4];
  const float* Wk  = (const float*)d_in[5];
  const float* Wv  = (const float*)d_in[6];
  const float* W1  = (const float*)d_in[7];
  const float* b1  = (const float*)d_in[8];
  const float* W2  = (const float*)d_in[9];
  const float* b2  = (const float*)d_in[10];
  const float* Wo  = (const float*)d_in[11];
  const float* bo  = (const float*)d_in[12];
  float* out = (float*)d_out;
  char* ws = (char*)d_ws;
  float*  wkvf = (float*)(ws + OFF_KVF32);
  ushort* wfr  = (ushort*)ws;

  wkv_kernel<<<dim3(256), dim3(256), 0, stream>>>(Wk, Wv, wkvf);
  pack_kernel<<<dim3(640), dim3(64), 0, stream>>>(Wq, Wk, wkvf, W1, W2, Wo, wfr);
  fused_main<<<dim3(2048), dim3(512), 0, stream>>>(q, k, pos, msk, b1, b2, bo, wfr, out);
}